// Round 11
// baseline (17620.049 us; speedup 1.0000x reference)
//
#include <hip/hip_runtime.h>

typedef unsigned short u16;
typedef unsigned int u32;
typedef unsigned long long u64;
typedef __attribute__((ext_vector_type(8))) short bf16x8;   // 8 bf16 (4 VGPRs)
typedef __attribute__((ext_vector_type(4))) float f32x4;

#define T_STEPS 1024
#define E_SZ 128
#define U_SZ 256

#define NG 16    // batch groups (16 batches each)
#define MB 16    // batch rows per group
#define NSL 8    // slices per layer (8 L0-wgs + 8 L1-wgs per group)
#define RD 8     // h0 ring depth
#define HS 264   // padded LDS row stride (epilogue gather)
#define EPAD 136 // padded LDS row stride, K=128

// ---- LDS layout (role-dependent), bytes ----
#define L0_W0T 0                 // 128*136*2 = 34816
#define L0_R0T 34816             // 128*264*2 = 67584
#define L0_G   102400            // 2 x 8704 (double-buffered gates)
#define L0_B   119808            // 512
#define L1_W1T 0                 // 67584
#define L1_R1T 67584             // 67584
#define L1_G   135168            // 2 x 8704
#define L1_EPI 152576            // 8448
#define L1_B   161024            // 512
#define SMEM_TOTAL 161536        // <= 163840

// ---- exchange state (module globals); agent scope = proven correct ----
// Block = 1KB: 16 rows (batch) x 64B (32 units bf16). Wave wv owns rows 4wv..4wv+3.
__device__ u64 g_exH0[RD * NG * NSL * 128];  // 1 MiB: h0 ring
__device__ u64 g_exH1[2 * NG * NSL * 128];   // 256 KiB: h1 parity ring
__device__ int g_f0[NG * 512];               // 32 flags/group (sl*4+wv), 64B apart
__device__ int g_f1[NG * 512];
__device__ int g_pr[NG * NSL * 16];          // L1 consume progress (ring guard)
__device__ int g_isF32;

__device__ __forceinline__ float bf2f(u16 u) {
  union { u32 i; float f; } v; v.i = ((u32)u) << 16; return v.f;
}
__device__ __forceinline__ u16 f2bf(float f) {
  union { u32 i; float f; } v; v.f = f;
  u32 r = v.i + 0x7fffu + ((v.i >> 16) & 1u);
  return (u16)(r >> 16);
}
__device__ __forceinline__ float sig_(float x) { return 1.f / (1.f + __expf(-x)); }
__device__ __forceinline__ float tnh_(float x) { return 2.f / (1.f + __expf(-2.f * x)) - 1.f; }

// ---- dtype probe: zeroes sync state each call ----
extern "C" __global__ void dtype_probe(const void* W0v) {
  __shared__ int cntBig;
  if (threadIdx.x == 0) cntBig = 0;
  __syncthreads();
  const u16* u = (const u16*)W0v;
  int big = 0;
  for (int i = threadIdx.x; i < 4096; i += 256)
    if ((u[i] & 0x7F80u) >= 0x4100u) big++;
  atomicAdd(&cntBig, big);
  __syncthreads();
  for (int i = threadIdx.x; i < NG * 512; i += 256) { g_f0[i] = 0; g_f1[i] = 0; }
  for (int i = threadIdx.x; i < NG * NSL * 16; i += 256) g_pr[i] = 0;
  if (threadIdx.x == 0) g_isF32 = (cntBig > 100) ? 1 : 0;
}

// ---- wave-parallel dual poll: lanes 0-31 poll 32 flags of set A (>= tA),
// lanes 32-63 poll set B (>= tB) if present. Whole rendezvous ~1 RTT. ----
__device__ __forceinline__ void pollDual(const int* fA, int tA,
                                         const int* fB, int tB,
                                         int lane, int* sAb) {
  const int* p = nullptr; int tgt = 0;
  if (lane < 32) { p = fA + lane * 16; tgt = tA; }
  else if (fB) { p = fB + (lane - 32) * 16; tgt = tB; }
  int ok = (p == nullptr);
  int it = 0;
  while (!__all(ok)) {
    if (*sAb) break;
    if (!ok)
      ok = __hip_atomic_load(p, __ATOMIC_RELAXED, __HIP_MEMORY_SCOPE_AGENT) >= tgt;
    if (++it > 48) __builtin_amdgcn_s_sleep(1);
    if (it > 400000) { *sAb = 1; break; }
  }
  __atomic_signal_fence(__ATOMIC_ACQUIRE);
}

// ---- ring-guard poll returning min observed progress (amortized) ----
__device__ __forceinline__ int wavePollMin(const int* fA, int tgt, int lane, int* sAb) {
  const int* p = (lane < 8) ? fA + lane * 16 : nullptr;
  int ok = (p == nullptr);
  int v = 0x7fffffff;
  int it = 0;
  while (!__all(ok)) {
    if (*sAb) break;
    if (!ok) {
      v = __hip_atomic_load(p, __ATOMIC_RELAXED, __HIP_MEMORY_SCOPE_AGENT);
      ok = v >= tgt;
    }
    if (++it > 48) __builtin_amdgcn_s_sleep(1);
    if (it > 400000) { *sAb = 1; break; }
  }
  __atomic_signal_fence(__ATOMIC_ACQUIRE);
  int m = (lane < 8) ? v : 0x7fffffff;
#pragma unroll
  for (int off = 4; off; off >>= 1) {
    int o = __shfl_down(m, off);
    m = m < o ? m : o;
  }
  return __shfl(m, 0);
}

// ---- load my 16B A-fragment of a peer slice block ----
__device__ __forceinline__ bf16x8 loadFrag(const u64* __restrict__ exch, u64 blk,
                                           int ml, int quad) {
  union { u64 q[2]; bf16x8 v; } f;
  const u64* p = exch + blk * 128 + (ml << 3) + (quad << 1);
  f.q[0] = __hip_atomic_load(p, __ATOMIC_RELAXED, __HIP_MEMORY_SCOPE_AGENT);
  f.q[1] = __hip_atomic_load(p + 1, __ATOMIC_RELAXED, __HIP_MEMORY_SCOPE_AGENT);
  return f.v;
}

// ---- epilogue gather: 8 blocks -> LDS ----
__device__ __forceinline__ void readBlks(const u64* __restrict__ exch, u64 slot0,
                                         int tid, u16* __restrict__ ldsH) {
  const int sp = tid >> 5, q2 = tid & 31;
  const u64* src = exch + (slot0 + sp) * 128 + (q2 << 2);
  const int m = q2 >> 1, half = q2 & 1;
  u16* dst = ldsH + m * HS + (sp << 5) + (half << 4);
#pragma unroll
  for (int j = 0; j < 4; j++) {
    u64 v = __hip_atomic_load(src + j,
                              __ATOMIC_RELAXED, __HIP_MEMORY_SCOPE_AGENT);
    *(u64*)(dst + (j << 2)) = v;
  }
}

extern "C" __global__ void __launch_bounds__(256, 1)
lstm_fused(const int* __restrict__ tokens, const void* __restrict__ emb,
           const void* __restrict__ W0, const void* __restrict__ R0, const void* __restrict__ b0,
           const void* __restrict__ W1, const void* __restrict__ R1, const void* __restrict__ b1,
           const void* __restrict__ Wout, const void* __restrict__ bout,
           void* __restrict__ outv) {
  extern __shared__ char smem[];
  __shared__ int abortF;

  const int tid = threadIdx.x;
  const int b = blockIdx.x;
  const int g = b & (NG - 1);
  const int w = b >> 4;
  const int role = w >> 3;             // 0 = layer-0 wg, 1 = layer-1 wg
  const int sl = w & 7;
  const int isF32 = g_isF32;

  if (tid == 0) abortF = 0;

  auto ldf = [&](const void* p, int idx) -> float {
    return isF32 ? ((const float*)p)[idx] : bf2f(((const u16*)p)[idx]);
  };

  const int lane = tid & 63;
  const int wv = tid >> 6;            // wave = gate q (output tiles 2wv, 2wv+1)
  const int ml = lane & 15;
  const int quad = lane >> 4;
  const int um = tid >> 4;
  const int un = tid & 15;

  int* f0base = g_f0 + (g << 9);      // this group's 32 h0 flags
  int* f1base = g_f1 + (g << 9);
  int* flp = g_pr + (g << 3) * 16;

  // cell-update lane mapping (per wave): row mrow, units uu, uu+1
  const int mrow = (wv << 2) + (lane >> 4);
  const int uu = (lane & 15) << 1;

  if (role == 0) {
    // ================= LAYER-0 WORKGROUP =================
    u16* w0t = (u16*)(smem + L0_W0T);
    u16* r0t = (u16*)(smem + L0_R0T);
    float* ldsG = (float*)(smem + L0_G);
    float* ldsB = (float*)(smem + L0_B);

    for (int i = tid; i < 128 * 128; i += 256) {
      int k = i >> 7, n = i & 127;
      int col = ((n >> 5) << 8) + (sl << 5) + (n & 31);
      w0t[n * EPAD + k] = f2bf(ldf(W0, k * 1024 + col));
    }
    for (int i = tid; i < 128 * 256; i += 256) {
      int k = i >> 7, n = i & 127;
      int col = ((n >> 5) << 8) + (sl << 5) + (n & 31);
      r0t[n * HS + k] = f2bf(ldf(R0, k * 1024 + col));
    }
    if (tid < 128) {
      int col = ((tid >> 5) << 8) + (sl << 5) + (tid & 31);
      ldsB[tid] = ldf(b0, col);
    }

    float cst[2] = {0.f, 0.f};
    int prMin = 0;
    const int tokRow = (g * MB + ml) * T_STEPS;   // batch row = ml (A-frag row)

    // x-fragment register prefetch (direct from emb, no LDS staging):
    // lane (ml,quad) needs x[ml][c*32 + quad*8 .. +7] for chunks c=0..3
    float4 xf[8]; uint4 xb[4];
    {
      int tok = tokens[tokRow];
      if (isF32) {
        const float* rowp = (const float*)emb + (u64)tok * E_SZ + (quad << 3);
#pragma unroll
        for (int c = 0; c < 4; c++) {
          xf[2 * c] = *(const float4*)(rowp + c * 32);
          xf[2 * c + 1] = *(const float4*)(rowp + c * 32 + 4);
        }
      } else {
        const u16* rowp = (const u16*)emb + (u64)tok * E_SZ + (quad << 3);
#pragma unroll
        for (int c = 0; c < 4; c++) xb[c] = *(const uint4*)(rowp + c * 32);
      }
    }
    __syncthreads();

    const int row0 = (wv << 5) + ml;
    const u16* brA0 = w0t + row0 * EPAD + (quad << 3);
    const u16* brB0 = brA0 + (EPAD << 4);
    const u16* brA2 = r0t + row0 * HS + (quad << 3);
    const u16* brB2 = brA2 + (HS << 4);

    for (int t = 0; t < T_STEPS; t++) {
      float* gcur = ldsG + (t & 1) * 2176;
      float ba = ldsB[row0], bb = ldsB[row0 + 16];
      f32x4 acA = {ba, ba, ba, ba}, acB = {bb, bb, bb, bb};

      // x_t @ W0 from register fragments
#pragma unroll
      for (int c = 0; c < 4; c++) {
        union { u16 h[8]; bf16x8 v; } cv;
        if (isF32) {
          float4 a = xf[2 * c], d = xf[2 * c + 1];
          cv.h[0] = f2bf(a.x); cv.h[1] = f2bf(a.y); cv.h[2] = f2bf(a.z); cv.h[3] = f2bf(a.w);
          cv.h[4] = f2bf(d.x); cv.h[5] = f2bf(d.y); cv.h[6] = f2bf(d.z); cv.h[7] = f2bf(d.w);
        } else {
          *(uint4*)cv.h = xb[c];
        }
        acA = __builtin_amdgcn_mfma_f32_16x16x32_bf16(cv.v, *(const bf16x8*)(brA0 + c * 32), acA, 0, 0, 0);
        acB = __builtin_amdgcn_mfma_f32_16x16x32_bf16(cv.v, *(const bf16x8*)(brB0 + c * 32), acB, 0, 0, 0);
      }

      // issue x_{t+1} prefetch (in flight across the rendezvous below)
      if (t + 1 < T_STEPS) {
        int tok = tokens[tokRow + t + 1];
        if (isF32) {
          const float* rowp = (const float*)emb + (u64)tok * E_SZ + (quad << 3);
#pragma unroll
          for (int c = 0; c < 4; c++) {
            xf[2 * c] = *(const float4*)(rowp + c * 32);
            xf[2 * c + 1] = *(const float4*)(rowp + c * 32 + 4);
          }
        } else {
          const u16* rowp = (const u16*)emb + (u64)tok * E_SZ + (quad << 3);
#pragma unroll
          for (int c = 0; c < 4; c++) xb[c] = *(const uint4*)(rowp + c * 32);
        }
      }

      // h0_{t-1} @ R0: 1-RTT poll of 32 flags, then 8 pipelined frag loads
      if (t > 0) {
        pollDual(f0base, t, nullptr, 0, lane, &abortF);
        const u64 s0 = (u64)((((t - 1) & (RD - 1)) * NG + g) * NSL);
        bf16x8 fr[NSL];
#pragma unroll
        for (int j = 0; j < NSL; j++) fr[j] = loadFrag(g_exH0, s0 + j, ml, quad);
#pragma unroll
        for (int j = 0; j < NSL; j++) {
          acA = __builtin_amdgcn_mfma_f32_16x16x32_bf16(fr[j], *(const bf16x8*)(brA2 + (j << 5)), acA, 0, 0, 0);
          acB = __builtin_amdgcn_mfma_f32_16x16x32_bf16(fr[j], *(const bf16x8*)(brB2 + (j << 5)), acB, 0, 0, 0);
        }
      }

      // gates -> double-buffered LDS
#pragma unroll
      for (int r = 0; r < 4; r++) {
        int m = (quad << 2) + r;
        float gA = (wv == 2) ? tnh_(acA[r]) : sig_(acA[r]);
        float gB = (wv == 2) ? tnh_(acB[r]) : sig_(acB[r]);
        gcur[row0 * 17 + m] = gA;
        gcur[(row0 + 16) * 17 + m] = gB;
      }
      __syncthreads();   // the ONLY barrier per step

      // ring guard (amortized; off critical path most steps)
      if (t >= RD && prMin < t - RD + 1)
        prMin = wavePollMin(flp, t - RD + 1, lane, &abortF);

      // cell update (wave-local rows) + direct quarter post + per-wave flag
      {
        float iv0 = gcur[uu * 17 + mrow];
        float fv0 = gcur[(32 + uu) * 17 + mrow];
        float gg0 = gcur[(64 + uu) * 17 + mrow];
        float ov0 = gcur[(96 + uu) * 17 + mrow];
        float iv1 = gcur[(uu + 1) * 17 + mrow];
        float fv1 = gcur[(33 + uu) * 17 + mrow];
        float gg1 = gcur[(65 + uu) * 17 + mrow];
        float ov1 = gcur[(97 + uu) * 17 + mrow];
        cst[0] = fv0 * cst[0] + iv0 * gg0;
        cst[1] = fv1 * cst[1] + iv1 * gg1;
        u32 wd = ((u32)f2bf(ov1 * tnh_(cst[1])) << 16) | (u32)f2bf(ov0 * tnh_(cst[0]));
        u64 blk = (u64)(((t & (RD - 1)) * NG + g) * NSL + sl);
        u32* dst = (u32*)(g_exH0 + blk * 128);
        __hip_atomic_store(dst + (mrow << 4) + (lane & 15), wd,
                           __ATOMIC_RELAXED, __HIP_MEMORY_SCOPE_AGENT);
        __builtin_amdgcn_fence(__ATOMIC_RELEASE, "agent");
        if (lane == 0)
          __hip_atomic_store(f0base + ((sl << 2) + wv) * 16, t + 1,
                             __ATOMIC_RELAXED, __HIP_MEMORY_SCOPE_AGENT);
      }
    }
  } else {
    // ================= LAYER-1 WORKGROUP =================
    u16* w1t = (u16*)(smem + L1_W1T);
    u16* r1t = (u16*)(smem + L1_R1T);
    float* ldsG = (float*)(smem + L1_G);
    u16* ldsEpi = (u16*)(smem + L1_EPI);
    float* ldsB = (float*)(smem + L1_B);

    for (int i = tid; i < 128 * 256; i += 256) {
      int k = i >> 7, n = i & 127;
      int col = ((n >> 5) << 8) + (sl << 5) + (n & 31);
      w1t[n * HS + k] = f2bf(ldf(W1, k * 1024 + col));
      r1t[n * HS + k] = f2bf(ldf(R1, k * 1024 + col));
    }
    if (tid < 128) {
      int col = ((tid >> 5) << 8) + (sl << 5) + (tid & 31);
      ldsB[tid] = ldf(b1, col);
    }
    __syncthreads();

    float cst[2] = {0.f, 0.f};
    const int row0 = (wv << 5) + ml;
    const u16* brA1 = w1t + row0 * HS + (quad << 3);
    const u16* brB1 = brA1 + (HS << 4);
    const u16* brA2 = r1t + row0 * HS + (quad << 3);
    const u16* brB2 = brA2 + (HS << 4);

    for (int t = 0; t < T_STEPS; t++) {
      float* gcur = ldsG + (t & 1) * 2176;
      float ba = ldsB[row0], bb = ldsB[row0 + 16];
      f32x4 acA = {ba, ba, ba, ba}, acB = {bb, bb, bb, bb};

      // ONE combined 1-RTT poll: 32 h0_t flags + 32 h1_{t-1} flags
      pollDual(f0base, t + 1, (t > 0) ? f1base : nullptr, t, lane, &abortF);

      // batch-load all fragments (pipelined, ~1 RTT)
      bf16x8 fr0[NSL], fr1[NSL];
      const u64 s0 = (u64)(((t & (RD - 1)) * NG + g) * NSL);
#pragma unroll
      for (int j = 0; j < NSL; j++) fr0[j] = loadFrag(g_exH0, s0 + j, ml, quad);
      if (t > 0) {
        const u64 s1 = (u64)((((t - 1) & 1) * NG + g) * NSL);
#pragma unroll
        for (int j = 0; j < NSL; j++) fr1[j] = loadFrag(g_exH1, s1 + j, ml, quad);
      }

      // h0_t @ W1
#pragma unroll
      for (int j = 0; j < NSL; j++) {
        acA = __builtin_amdgcn_mfma_f32_16x16x32_bf16(fr0[j], *(const bf16x8*)(brA1 + (j << 5)), acA, 0, 0, 0);
        acB = __builtin_amdgcn_mfma_f32_16x16x32_bf16(fr0[j], *(const bf16x8*)(brB1 + (j << 5)), acB, 0, 0, 0);
      }
      // h1_{t-1} @ R1
      if (t > 0) {
#pragma unroll
        for (int j = 0; j < NSL; j++) {
          acA = __builtin_amdgcn_mfma_f32_16x16x32_bf16(fr1[j], *(const bf16x8*)(brA2 + (j << 5)), acA, 0, 0, 0);
          acB = __builtin_amdgcn_mfma_f32_16x16x32_bf16(fr1[j], *(const bf16x8*)(brB2 + (j << 5)), acB, 0, 0, 0);
        }
      }

      // gates -> double-buffered LDS
#pragma unroll
      for (int r = 0; r < 4; r++) {
        int m = (quad << 2) + r;
        float gA = (wv == 2) ? tnh_(acA[r]) : sig_(acA[r]);
        float gB = (wv == 2) ? tnh_(acB[r]) : sig_(acB[r]);
        gcur[row0 * 17 + m] = gA;
        gcur[(row0 + 16) * 17 + m] = gB;
      }
      __syncthreads();   // the ONLY barrier per step

      // ring-slot release (all waves' h0 frag loads consumed before barrier)
      if (tid == 0) {
        __atomic_signal_fence(__ATOMIC_RELEASE);
        __hip_atomic_store(g_pr + ((g << 3) + sl) * 16, t + 1,
                           __ATOMIC_RELAXED, __HIP_MEMORY_SCOPE_AGENT);
      }

      // cell update + direct quarter post + per-wave flag
      {
        float iv0 = gcur[uu * 17 + mrow];
        float fv0 = gcur[(32 + uu) * 17 + mrow];
        float gg0 = gcur[(64 + uu) * 17 + mrow];
        float ov0 = gcur[(96 + uu) * 17 + mrow];
        float iv1 = gcur[(uu + 1) * 17 + mrow];
        float fv1 = gcur[(33 + uu) * 17 + mrow];
        float gg1 = gcur[(65 + uu) * 17 + mrow];
        float ov1 = gcur[(97 + uu) * 17 + mrow];
        cst[0] = fv0 * cst[0] + iv0 * gg0;
        cst[1] = fv1 * cst[1] + iv1 * gg1;
        u32 wd = ((u32)f2bf(ov1 * tnh_(cst[1])) << 16) | (u32)f2bf(ov0 * tnh_(cst[0]));
        u64 blk = (u64)(((t & 1) * NG + g) * NSL + sl);
        u32* dst = (u32*)(g_exH1 + blk * 128);
        __hip_atomic_store(dst + (mrow << 4) + (lane & 15), wd,
                           __ATOMIC_RELAXED, __HIP_MEMORY_SCOPE_AGENT);
        __builtin_amdgcn_fence(__ATOMIC_RELEASE, "agent");
        if (lane == 0)
          __hip_atomic_store(f1base + ((sl << 2) + wv) * 16, t + 1,
                             __ATOMIC_RELAXED, __HIP_MEMORY_SCOPE_AGENT);
      }
    }

    // ---- epilogue: logits from h1_{T-1} ----
    if (sl == 0) {
      pollDual(f1base, T_STEPS, nullptr, 0, lane, &abortF);
      __syncthreads();
      readBlks(g_exH1, (u64)(((T_STEPS - 1) & 1) * NG + g) * NSL, tid, ldsEpi);
      __syncthreads();
      float* woutf = ldsG;
      float* red = ldsG + 272;
      woutf[tid] = ldf(Wout, tid);
      __syncthreads();
      float pacc = 0.f;
#pragma unroll
      for (int j = 0; j < 16; j++)
        pacc += bf2f(ldsEpi[um * HS + (un << 4) + j]) * woutf[(un << 4) + j];
      red[um * 17 + un] = pacc;
      __syncthreads();
      if (tid < 16) {
        float sum = ldf(bout, 0);
#pragma unroll
        for (int j = 0; j < 16; j++) sum += red[tid * 17 + j];
        float val = sig_(sum);
        if (isF32) ((float*)outv)[g * MB + tid] = val;
        else       ((u16*)outv)[g * MB + tid] = f2bf(val);
      }
    }
  }
}

extern "C" void kernel_launch(void* const* d_in, const int* in_sizes, int n_in,
                              void* d_out, int out_size, void* d_ws, size_t ws_size,
                              hipStream_t stream) {
  const int* tokens = (const int*)d_in[0];
  const void* emb  = d_in[1];
  const void* W0   = d_in[2];
  const void* R0   = d_in[3];
  const void* b0   = d_in[4];
  const void* W1   = d_in[5];
  const void* R1   = d_in[6];
  const void* b1   = d_in[7];
  const void* Wout = d_in[8];
  const void* bout = d_in[9];

  hipFuncSetAttribute((const void*)lstm_fused,
                      hipFuncAttributeMaxDynamicSharedMemorySize, SMEM_TOTAL);

  dtype_probe<<<dim3(1), dim3(256), 0, stream>>>(W0);

  // 256 wgs (16 groups x (8 L0 + 8 L1)), 1 wg/CU: co-resident.
  lstm_fused<<<dim3(256), dim3(256), SMEM_TOTAL, stream>>>(
      tokens, emb, W0, R0, b0, W1, R1, b1, Wout, bout, d_out);
}

// Round 12
// 7518.838 us; speedup vs baseline: 2.3435x; 2.3435x over previous
//
#include <hip/hip_runtime.h>

typedef unsigned short u16;
typedef unsigned int u32;
typedef unsigned long long u64;
typedef __attribute__((ext_vector_type(8))) short bf16x8;   // 8 bf16 (4 VGPRs)
typedef __attribute__((ext_vector_type(4))) float f32x4;

#define T_STEPS 1024
#define E_SZ 128
#define U_SZ 256

#define NG 16    // batch groups (16 batches each)
#define MB 16    // batch rows per group
#define NSL 8    // slices per layer (8 L0-wgs + 8 L1-wgs per group)
#define RD 8     // h0 ring depth
#define HS 264   // padded LDS row stride, K=256
#define EPAD 136 // padded LDS row stride, K=128

// ---- LDS layout (role-dependent), bytes ----
#define L0_W0T 0
#define L0_R0T 34816
#define L0_X   102400
#define L0_G   106752
#define L0_STG 115456
#define L0_B   116480
#define L1_W1T 0
#define L1_R1T 67584
#define L1_EPI 135168
#define L1_G   143616
#define L1_STG 152320
#define L1_B   153344
#define SMEM_TOTAL 153856

// ---- exchange state (module globals); agent scope = proven correct ----
__device__ u64 g_exH0[RD * NG * NSL * 128];  // 1 MiB: h0 ring, 1KB/slice-block
__device__ u64 g_exH1[2 * NG * NSL * 128];   // 256 KiB: h1 parity ring
__device__ int g_f0[NG * NSL * 16];          // h0 flags, one 64B line each
__device__ int g_f1[NG * NSL * 16];          // h1 flags
__device__ int g_pr[NG * NSL * 16];          // L1 consume progress (ring guard)
__device__ int g_isF32;

__device__ __forceinline__ float bf2f(u16 u) {
  union { u32 i; float f; } v; v.i = ((u32)u) << 16; return v.f;
}
__device__ __forceinline__ u16 f2bf(float f) {
  union { u32 i; float f; } v; v.f = f;
  u32 r = v.i + 0x7fffu + ((v.i >> 16) & 1u);
  return (u16)(r >> 16);
}
__device__ __forceinline__ float sig_(float x) { return 1.f / (1.f + __expf(-x)); }
__device__ __forceinline__ float tnh_(float x) { return 2.f / (1.f + __expf(-2.f * x)) - 1.f; }

// ---- dtype probe: zeroes sync state each call ----
extern "C" __global__ void dtype_probe(const void* W0v) {
  __shared__ int cntBig;
  if (threadIdx.x == 0) cntBig = 0;
  __syncthreads();
  const u16* u = (const u16*)W0v;
  int big = 0;
  for (int i = threadIdx.x; i < 4096; i += 256)
    if ((u[i] & 0x7F80u) >= 0x4100u) big++;
  atomicAdd(&cntBig, big);
  __syncthreads();
  for (int i = threadIdx.x; i < NG * NSL * 16; i += 256) {
    g_f0[i] = 0; g_f1[i] = 0; g_pr[i] = 0;
  }
  if (threadIdx.x == 0) g_isF32 = (cntBig > 100) ? 1 : 0;
}

// ---- wave-parallel poll: lanes 0-7 poll set A (>= tA), lanes 8-15 set B.
// HOT SPIN: each poll iter is a ~900cyc dependent agent load — that IS the
// backoff; s_sleep only quantizes the observe (R11 post-mortem). ----
__device__ __forceinline__ void wavePoll(const int* fA, int tA,
                                         const int* fB, int tB, int lane) {
  const int* p = nullptr; int tgt = 0;
  if (lane < 8) { p = fA + lane * 16; tgt = tA; }
  else if (lane < 16 && fB) { p = fB + (lane - 8) * 16; tgt = tB; }
  int ok = (p == nullptr);
  int it = 0;
  while (!__all(ok)) {
    if (!ok)
      ok = __hip_atomic_load(p, __ATOMIC_RELAXED, __HIP_MEMORY_SCOPE_AGENT) >= tgt;
    if (++it > 2048) __builtin_amdgcn_s_sleep(1);
    if (it > 500000) break;   // deadlock -> terminate (wrong answer, not hang)
  }
  __atomic_signal_fence(__ATOMIC_ACQUIRE);
}

// ---- ring-guard poll returning min observed progress (amortizes re-polls) ----
__device__ __forceinline__ int wavePollMin(const int* fA, int tgt, int lane) {
  const int* p = (lane < 8) ? fA + lane * 16 : nullptr;
  int ok = (p == nullptr);
  int v = 0x7fffffff;
  int it = 0;
  while (!__all(ok)) {
    if (!ok) {
      v = __hip_atomic_load(p, __ATOMIC_RELAXED, __HIP_MEMORY_SCOPE_AGENT);
      ok = v >= tgt;
    }
    if (++it > 2048) __builtin_amdgcn_s_sleep(1);
    if (it > 500000) break;
  }
  __atomic_signal_fence(__ATOMIC_ACQUIRE);
  int m = (lane < 8) ? v : 0x7fffffff;
#pragma unroll
  for (int off = 4; off; off >>= 1) {
    int o = __shfl_down(m, off);
    m = m < o ? m : o;
  }
  return __shfl(m, 0);
}

// ---- load my 16B A-fragment of peer slice block (independent, pipelined) ----
__device__ __forceinline__ bf16x8 loadFrag(const u64* __restrict__ exch, u64 blk,
                                           int ml, int quad) {
  union { u64 q[2]; bf16x8 v; } f;
  const u64* p = exch + blk * 128 + (ml << 3) + (quad << 1);
  f.q[0] = __hip_atomic_load(p, __ATOMIC_RELAXED, __HIP_MEMORY_SCOPE_AGENT);
  f.q[1] = __hip_atomic_load(p + 1, __ATOMIC_RELAXED, __HIP_MEMORY_SCOPE_AGENT);
  return f.v;
}

// ---- post one 1KB slice block (wave 0): data -> release fence -> flag ----
__device__ __forceinline__ void postBlk(u64* __restrict__ exch, u64 blk,
                                        int* __restrict__ flags, int fidx, int val,
                                        int tid, const u16* __restrict__ stg) {
  if (tid < 64) {
    const u64* sp = (const u64*)stg;
    u64* dst = exch + blk * 128 + (tid << 1);
    __hip_atomic_store(dst, sp[tid << 1],
                       __ATOMIC_RELAXED, __HIP_MEMORY_SCOPE_AGENT);
    __hip_atomic_store(dst + 1, sp[(tid << 1) + 1],
                       __ATOMIC_RELAXED, __HIP_MEMORY_SCOPE_AGENT);
    __builtin_amdgcn_fence(__ATOMIC_RELEASE, "agent");
    if (tid == 0)
      __hip_atomic_store(flags + fidx * 16, val,
                         __ATOMIC_RELAXED, __HIP_MEMORY_SCOPE_AGENT);
  }
}

// ---- block-wide wait on 8 flags (epilogue only) ----
__device__ __forceinline__ void waitF8(int* __restrict__ flags, int g, int target,
                                       int tid) {
  if (tid < 8) {
    int it = 0;
    const int* p = flags + ((g << 3) + tid) * 16;
    while (__hip_atomic_load(p, __ATOMIC_RELAXED, __HIP_MEMORY_SCOPE_AGENT) < target) {
      if (++it > 300000) break;
      if (it > 2048) __builtin_amdgcn_s_sleep(2);
    }
  }
  __syncthreads();
  __atomic_signal_fence(__ATOMIC_ACQUIRE);
}

// ---- epilogue gather: 8 blocks -> LDS ----
__device__ __forceinline__ void readBlks(const u64* __restrict__ exch, u64 slot0,
                                         int tid, u16* __restrict__ ldsH) {
  const int sp = tid >> 5, q2 = tid & 31;
  const u64* src = exch + (slot0 + sp) * 128 + (q2 << 2);
  const int m = q2 >> 1, half = q2 & 1;
  u16* dst = ldsH + m * HS + (sp << 5) + (half << 4);
#pragma unroll
  for (int j = 0; j < 4; j++) {
    u64 v = __hip_atomic_load(src + j,
                              __ATOMIC_RELAXED, __HIP_MEMORY_SCOPE_AGENT);
    *(u64*)(dst + (j << 2)) = v;
  }
}

extern "C" __global__ void __launch_bounds__(256, 1)
lstm_fused(const int* __restrict__ tokens, const void* __restrict__ emb,
           const void* __restrict__ W0, const void* __restrict__ R0, const void* __restrict__ b0,
           const void* __restrict__ W1, const void* __restrict__ R1, const void* __restrict__ b1,
           const void* __restrict__ Wout, const void* __restrict__ bout,
           void* __restrict__ outv) {
  extern __shared__ char smem[];

  const int tid = threadIdx.x;
  const int b = blockIdx.x;
  const int g = b & (NG - 1);
  const int w = b >> 4;
  const int role = w >> 3;             // 0 = layer-0 wg, 1 = layer-1 wg
  const int sl = w & 7;
  const int isF32 = g_isF32;

  auto ldf = [&](const void* p, int idx) -> float {
    return isF32 ? ((const float*)p)[idx] : bf2f(((const u16*)p)[idx]);
  };

  const int lane = tid & 63;
  const int wv = tid >> 6;            // wave = gate q (output tiles 2wv, 2wv+1)
  const int ml = lane & 15;
  const int quad = lane >> 4;
  const int um = tid >> 4;
  const int un = tid & 15;

  int* fl0 = g_f0 + (g << 3) * 16;    // this group's 8 h0 flags
  int* fl1 = g_f1 + (g << 3) * 16;
  int* flp = g_pr + (g << 3) * 16;

  if (role == 0) {
    // ================= LAYER-0 WORKGROUP =================
    u16* w0t = (u16*)(smem + L0_W0T);
    u16* r0t = (u16*)(smem + L0_R0T);
    u16* ldsX = (u16*)(smem + L0_X);
    float* ldsG = (float*)(smem + L0_G);
    u16* stg = (u16*)(smem + L0_STG);
    float* ldsB = (float*)(smem + L0_B);

    for (int i = tid; i < 128 * 128; i += 256) {
      int k = i >> 7, n = i & 127;
      int col = ((n >> 5) << 8) + (sl << 5) + (n & 31);
      w0t[n * EPAD + k] = f2bf(ldf(W0, k * 1024 + col));
    }
    for (int i = tid; i < 128 * 256; i += 256) {
      int k = i >> 7, n = i & 127;
      int col = ((n >> 5) << 8) + (sl << 5) + (n & 31);
      r0t[n * HS + k] = f2bf(ldf(R0, k * 1024 + col));
    }
    if (tid < 128) {
      int col = ((tid >> 5) << 8) + (sl << 5) + (tid & 31);
      ldsB[tid] = ldf(b0, col);
    }

    float cst[2] = {0.f, 0.f};
    const int tokBase = (g * MB + um) * T_STEPS;
    int prMin = 0;                    // cached min L1 progress (ring guard)

    float4 xfA, xfB; uint4 xbf;
    {
      int tok = tokens[tokBase];
      if (isF32) {
        const float* row = (const float*)emb + (u64)tok * E_SZ + (un << 3);
        xfA = *(const float4*)row; xfB = *(const float4*)(row + 4);
      } else {
        xbf = *(const uint4*)((const u16*)emb + (u64)tok * E_SZ + (un << 3));
      }
    }
    __syncthreads();

    const int row0 = (wv << 5) + ml;
    const u16* brA0 = w0t + row0 * EPAD + (quad << 3);
    const u16* brB0 = brA0 + (EPAD << 4);
    const u16* brA2 = r0t + row0 * HS + (quad << 3);
    const u16* brB2 = brA2 + (HS << 4);

    for (int t = 0; t < T_STEPS; t++) {
      // commit x_t
      {
        uint4 pk;
        if (isF32) {
          pk.x = (u32)f2bf(xfA.x) | ((u32)f2bf(xfA.y) << 16);
          pk.y = (u32)f2bf(xfA.z) | ((u32)f2bf(xfA.w) << 16);
          pk.z = (u32)f2bf(xfB.x) | ((u32)f2bf(xfB.y) << 16);
          pk.w = (u32)f2bf(xfB.z) | ((u32)f2bf(xfB.w) << 16);
        } else pk = xbf;
        *(uint4*)(ldsX + um * EPAD + (un << 3)) = pk;
      }
      __syncthreads();

      float ba = ldsB[row0], bb = ldsB[row0 + 16];
      f32x4 acA = {ba, ba, ba, ba}, acB = {bb, bb, bb, bb};

      // x_t @ W0 (no dependence on h0)
      {
        const u16* ar = ldsX + ml * EPAD + (quad << 3);
#pragma unroll
        for (int kc = 0; kc < 4; kc++) {
          bf16x8 av = *(const bf16x8*)(ar + kc * 32);
          acA = __builtin_amdgcn_mfma_f32_16x16x32_bf16(av, *(const bf16x8*)(brA0 + kc * 32), acA, 0, 0, 0);
          acB = __builtin_amdgcn_mfma_f32_16x16x32_bf16(av, *(const bf16x8*)(brB0 + kc * 32), acB, 0, 0, 0);
        }
      }

      // h0_{t-1} @ R0: one combined poll, then 16 pipelined frag loads
      if (t > 0) {
        wavePoll(fl0, t, nullptr, 0, lane);
        const u64 s0 = (u64)((((t - 1) & (RD - 1)) * NG + g) * NSL);
        bf16x8 fr[NSL];
#pragma unroll
        for (int j = 0; j < NSL; j++) fr[j] = loadFrag(g_exH0, s0 + j, ml, quad);
#pragma unroll
        for (int j = 0; j < NSL; j++) {
          acA = __builtin_amdgcn_mfma_f32_16x16x32_bf16(fr[j], *(const bf16x8*)(brA2 + (j << 5)), acA, 0, 0, 0);
          acB = __builtin_amdgcn_mfma_f32_16x16x32_bf16(fr[j], *(const bf16x8*)(brB2 + (j << 5)), acB, 0, 0, 0);
        }
      }

      // gates
#pragma unroll
      for (int r = 0; r < 4; r++) {
        int m = (quad << 2) + r;
        float gA = (wv == 2) ? tnh_(acA[r]) : sig_(acA[r]);
        float gB = (wv == 2) ? tnh_(acB[r]) : sig_(acB[r]);
        ldsG[row0 * 17 + m] = gA;
        ldsG[(row0 + 16) * 17 + m] = gB;
      }
      __syncthreads();

      // cell update -> stg
#pragma unroll
      for (int j = 0; j < 2; j++) {
        int idx = tid + (j << 8);
        int m = idx >> 5, uu = idx & 31;
        float iv = ldsG[uu * 17 + m];
        float fv = ldsG[(32 + uu) * 17 + m];
        float gv = ldsG[(64 + uu) * 17 + m];
        float ov = ldsG[(96 + uu) * 17 + m];
        float c = fv * cst[j] + iv * gv; cst[j] = c;
        stg[(m << 5) + uu] = f2bf(ov * tnh_(c));
      }
      __syncthreads();

      // ring guard, amortized: re-poll only when cached slack is spent
      if (t >= RD && prMin < t - RD + 1)
        prMin = wavePollMin(flp, t - RD + 1, lane);

      // post h0_t
      postBlk(g_exH0, (u64)(((t & (RD - 1)) * NG + g) * NSL + sl),
              g_f0, (g << 3) + sl, t + 1, tid, stg);

      // x_{t+1} prefetch in flight across next rendezvous
      if (t + 1 < T_STEPS) {
        int tok = tokens[tokBase + t + 1];
        if (isF32) {
          const float* row = (const float*)emb + (u64)tok * E_SZ + (un << 3);
          xfA = *(const float4*)row; xfB = *(const float4*)(row + 4);
        } else {
          xbf = *(const uint4*)((const u16*)emb + (u64)tok * E_SZ + (un << 3));
        }
      }
    }
  } else {
    // ================= LAYER-1 WORKGROUP =================
    u16* w1t = (u16*)(smem + L1_W1T);
    u16* r1t = (u16*)(smem + L1_R1T);
    u16* ldsEpi = (u16*)(smem + L1_EPI);
    float* ldsG = (float*)(smem + L1_G);
    u16* stg = (u16*)(smem + L1_STG);
    float* ldsB = (float*)(smem + L1_B);

    for (int i = tid; i < 128 * 256; i += 256) {
      int k = i >> 7, n = i & 127;
      int col = ((n >> 5) << 8) + (sl << 5) + (n & 31);
      w1t[n * HS + k] = f2bf(ldf(W1, k * 1024 + col));
      r1t[n * HS + k] = f2bf(ldf(R1, k * 1024 + col));
    }
    if (tid < 128) {
      int col = ((tid >> 5) << 8) + (sl << 5) + (tid & 31);
      ldsB[tid] = ldf(b1, col);
    }
    __syncthreads();

    float cst[2] = {0.f, 0.f};
    const int row0 = (wv << 5) + ml;
    const u16* brA1 = w1t + row0 * HS + (quad << 3);
    const u16* brB1 = brA1 + (HS << 4);
    const u16* brA2 = r1t + row0 * HS + (quad << 3);
    const u16* brB2 = brA2 + (HS << 4);

    for (int t = 0; t < T_STEPS; t++) {
      float ba = ldsB[row0], bb = ldsB[row0 + 16];
      f32x4 acA = {ba, ba, ba, ba}, acB = {bb, bb, bb, bb};

      // ONE combined poll: 8 h0_t flags + 8 h1_{t-1} flags (~1 RTT)
      wavePoll(fl0, t + 1, fl1, t, lane);

      // all 32 frag loads issued back-to-back (vmcnt-pipelined, ~1 RTT)
      bf16x8 fr0[NSL], fr1[NSL];
      const u64 s0 = (u64)(((t & (RD - 1)) * NG + g) * NSL);
#pragma unroll
      for (int j = 0; j < NSL; j++) fr0[j] = loadFrag(g_exH0, s0 + j, ml, quad);
      if (t > 0) {
        const u64 s1 = (u64)((((t - 1) & 1) * NG + g) * NSL);
#pragma unroll
        for (int j = 0; j < NSL; j++) fr1[j] = loadFrag(g_exH1, s1 + j, ml, quad);
      }

      // h0_t @ W1
#pragma unroll
      for (int j = 0; j < NSL; j++) {
        acA = __builtin_amdgcn_mfma_f32_16x16x32_bf16(fr0[j], *(const bf16x8*)(brA1 + (j << 5)), acA, 0, 0, 0);
        acB = __builtin_amdgcn_mfma_f32_16x16x32_bf16(fr0[j], *(const bf16x8*)(brB1 + (j << 5)), acB, 0, 0, 0);
      }
      // h1_{t-1} @ R1
      if (t > 0) {
#pragma unroll
        for (int j = 0; j < NSL; j++) {
          acA = __builtin_amdgcn_mfma_f32_16x16x32_bf16(fr1[j], *(const bf16x8*)(brA2 + (j << 5)), acA, 0, 0, 0);
          acB = __builtin_amdgcn_mfma_f32_16x16x32_bf16(fr1[j], *(const bf16x8*)(brB2 + (j << 5)), acB, 0, 0, 0);
        }
      }

      // gates
#pragma unroll
      for (int r = 0; r < 4; r++) {
        int m = (quad << 2) + r;
        float gA = (wv == 2) ? tnh_(acA[r]) : sig_(acA[r]);
        float gB = (wv == 2) ? tnh_(acB[r]) : sig_(acB[r]);
        ldsG[row0 * 17 + m] = gA;
        ldsG[(row0 + 16) * 17 + m] = gB;
      }
      __syncthreads();

      // ring-slot release (all waves' h0 loads are consumed by now)
      if (tid == 0) {
        __atomic_signal_fence(__ATOMIC_RELEASE);
        __hip_atomic_store(g_pr + ((g << 3) + sl) * 16, t + 1,
                           __ATOMIC_RELAXED, __HIP_MEMORY_SCOPE_AGENT);
      }

      // cell update -> stg
#pragma unroll
      for (int j = 0; j < 2; j++) {
        int idx = tid + (j << 8);
        int m = idx >> 5, uu = idx & 31;
        float iv = ldsG[uu * 17 + m];
        float fv = ldsG[(32 + uu) * 17 + m];
        float gv = ldsG[(64 + uu) * 17 + m];
        float ov = ldsG[(96 + uu) * 17 + m];
        float c = fv * cst[j] + iv * gv; cst[j] = c;
        stg[(m << 5) + uu] = f2bf(ov * tnh_(c));
      }
      __syncthreads();

      // post h1_t
      postBlk(g_exH1, (u64)(((t & 1) * NG + g) * NSL + sl),
              g_f1, (g << 3) + sl, t + 1, tid, stg);
    }

    // epilogue: logits from h1_{T-1}
    if (sl == 0) {
      waitF8(g_f1, g, T_STEPS, tid);
      readBlks(g_exH1, (u64)(((T_STEPS - 1) & 1) * NG + g) * NSL, tid, ldsEpi);
      __syncthreads();
      float* woutf = ldsG;
      float* red = ldsG + 272;
      woutf[tid] = ldf(Wout, tid);
      __syncthreads();
      float p = 0.f;
#pragma unroll
      for (int j = 0; j < 16; j++)
        p += bf2f(ldsEpi[um * HS + (un << 4) + j]) * woutf[(un << 4) + j];
      red[um * 17 + un] = p;
      __syncthreads();
      if (tid < 16) {
        float sum = ldf(bout, 0);
#pragma unroll
        for (int j = 0; j < 16; j++) sum += red[tid * 17 + j];
        float val = sig_(sum);
        if (isF32) ((float*)outv)[g * MB + tid] = val;
        else       ((u16*)outv)[g * MB + tid] = f2bf(val);
      }
    }
  }
}

extern "C" void kernel_launch(void* const* d_in, const int* in_sizes, int n_in,
                              void* d_out, int out_size, void* d_ws, size_t ws_size,
                              hipStream_t stream) {
  const int* tokens = (const int*)d_in[0];
  const void* emb  = d_in[1];
  const void* W0   = d_in[2];
  const void* R0   = d_in[3];
  const void* b0   = d_in[4];
  const void* W1   = d_in[5];
  const void* R1   = d_in[6];
  const void* b1   = d_in[7];
  const void* Wout = d_in[8];
  const void* bout = d_in[9];

  hipFuncSetAttribute((const void*)lstm_fused,
                      hipFuncAttributeMaxDynamicSharedMemorySize, SMEM_TOTAL);

  dtype_probe<<<dim3(1), dim3(256), 0, stream>>>(W0);

  // 256 wgs (16 groups x (8 L0 + 8 L1)), 1 wg/CU: co-resident.
  lstm_fused<<<dim3(256), dim3(256), SMEM_TOTAL, stream>>>(
      tokens, emb, W0, R0, b0, W1, R1, b1, Wout, bout, d_out);
}

// Round 13
// 6113.701 us; speedup vs baseline: 2.8821x; 1.2298x over previous
//
#include <hip/hip_runtime.h>

typedef unsigned short u16;
typedef unsigned int u32;
typedef unsigned long long u64;
typedef __attribute__((ext_vector_type(8))) short bf16x8;   // 8 bf16 (4 VGPRs)
typedef __attribute__((ext_vector_type(4))) float f32x4;

#define T_STEPS 1024
#define E_SZ 128
#define U_SZ 256

#define NG 16    // batch groups (16 batches each)
#define MB 16    // batch rows per group
#define NSL 8    // slices per layer (8 L0-wgs + 8 L1-wgs per group)
#define RD 8     // h0 ring depth
#define HS 264   // padded LDS row stride, K=256
#define EPAD 136 // padded LDS row stride, K=128

// ---- LDS layout (role-dependent), bytes ----
#define L0_W0T 0
#define L0_R0T 34816
#define L0_X   102400
#define L0_G   106752
#define L0_STG 115456
#define L0_B   116480
#define L1_W1T 0
#define L1_R1T 67584
#define L1_EPI 135168
#define L1_G   143616
#define L1_STG 152320
#define L1_B   153344
#define SMEM_TOTAL 153856

// ---- exchange state (module globals); agent scope = proven correct ----
__device__ u64 g_exH0[RD * NG * NSL * 128];  // 1 MiB: h0 ring, 1KB/slice-block
__device__ u64 g_exH1[2 * NG * NSL * 128];   // 256 KiB: h1 parity ring
__device__ int g_f0[NG * NSL * 16];          // h0 flags, one 64B line each
__device__ int g_f1[NG * NSL * 16];          // h1 flags
__device__ int g_pr[NG * NSL * 16];          // L1 consume progress (ring guard)
__device__ int g_isF32;

__device__ __forceinline__ float bf2f(u16 u) {
  union { u32 i; float f; } v; v.i = ((u32)u) << 16; return v.f;
}
__device__ __forceinline__ u16 f2bf(float f) {
  union { u32 i; float f; } v; v.f = f;
  u32 r = v.i + 0x7fffu + ((v.i >> 16) & 1u);
  return (u16)(r >> 16);
}
__device__ __forceinline__ float sig_(float x) { return 1.f / (1.f + __expf(-x)); }
__device__ __forceinline__ float tnh_(float x) { return 2.f / (1.f + __expf(-2.f * x)) - 1.f; }

// ---- dtype probe: zeroes sync state each call ----
extern "C" __global__ void dtype_probe(const void* W0v) {
  __shared__ int cntBig;
  if (threadIdx.x == 0) cntBig = 0;
  __syncthreads();
  const u16* u = (const u16*)W0v;
  int big = 0;
  for (int i = threadIdx.x; i < 4096; i += 256)
    if ((u[i] & 0x7F80u) >= 0x4100u) big++;
  atomicAdd(&cntBig, big);
  __syncthreads();
  for (int i = threadIdx.x; i < NG * NSL * 16; i += 256) {
    g_f0[i] = 0; g_f1[i] = 0; g_pr[i] = 0;
  }
  if (threadIdx.x == 0) g_isF32 = (cntBig > 100) ? 1 : 0;
}

// ---- wave-parallel poll: lanes 0-7 poll set A (>= tA), lanes 8-15 set B.
// R9-champion tuning: backoff after 48 iters (hot spin regressed — R12). ----
__device__ __forceinline__ void wavePoll(const int* fA, int tA,
                                         const int* fB, int tB, int lane) {
  const int* p = nullptr; int tgt = 0;
  if (lane < 8) { p = fA + lane * 16; tgt = tA; }
  else if (lane < 16 && fB) { p = fB + (lane - 8) * 16; tgt = tB; }
  int ok = (p == nullptr);
  int it = 0;
  while (!__all(ok)) {
    if (!ok)
      ok = __hip_atomic_load(p, __ATOMIC_RELAXED, __HIP_MEMORY_SCOPE_AGENT) >= tgt;
    if (++it > 48) __builtin_amdgcn_s_sleep(1);
    if (it > 500000) break;   // deadlock -> terminate (wrong answer, not hang)
  }
  __atomic_signal_fence(__ATOMIC_ACQUIRE);
}

// ---- ring-guard poll returning min observed progress (amortizes re-polls) ----
__device__ __forceinline__ int wavePollMin(const int* fA, int tgt, int lane) {
  const int* p = (lane < 8) ? fA + lane * 16 : nullptr;
  int ok = (p == nullptr);
  int v = 0x7fffffff;
  int it = 0;
  while (!__all(ok)) {
    if (!ok) {
      v = __hip_atomic_load(p, __ATOMIC_RELAXED, __HIP_MEMORY_SCOPE_AGENT);
      ok = v >= tgt;
    }
    if (++it > 48) __builtin_amdgcn_s_sleep(1);
    if (it > 500000) break;
  }
  __atomic_signal_fence(__ATOMIC_ACQUIRE);
  int m = (lane < 8) ? v : 0x7fffffff;
#pragma unroll
  for (int off = 4; off; off >>= 1) {
    int o = __shfl_down(m, off);
    m = m < o ? m : o;
  }
  return __shfl(m, 0);
}

// ---- load my 16B A-fragment of peer slice block (independent, pipelined) ----
__device__ __forceinline__ bf16x8 loadFrag(const u64* __restrict__ exch, u64 blk,
                                           int ml, int quad) {
  union { u64 q[2]; bf16x8 v; } f;
  const u64* p = exch + blk * 128 + (ml << 3) + (quad << 1);
  f.q[0] = __hip_atomic_load(p, __ATOMIC_RELAXED, __HIP_MEMORY_SCOPE_AGENT);
  f.q[1] = __hip_atomic_load(p + 1, __ATOMIC_RELAXED, __HIP_MEMORY_SCOPE_AGENT);
  return f.v;
}

// ---- post one 1KB slice block (wave 0): data -> release fence -> flag ----
__device__ __forceinline__ void postBlk(u64* __restrict__ exch, u64 blk,
                                        int* __restrict__ flags, int fidx, int val,
                                        int tid, const u16* __restrict__ stg) {
  if (tid < 64) {
    const u64* sp = (const u64*)stg;
    u64* dst = exch + blk * 128 + (tid << 1);
    __hip_atomic_store(dst, sp[tid << 1],
                       __ATOMIC_RELAXED, __HIP_MEMORY_SCOPE_AGENT);
    __hip_atomic_store(dst + 1, sp[(tid << 1) + 1],
                       __ATOMIC_RELAXED, __HIP_MEMORY_SCOPE_AGENT);
    __builtin_amdgcn_fence(__ATOMIC_RELEASE, "agent");
    if (tid == 0)
      __hip_atomic_store(flags + fidx * 16, val,
                         __ATOMIC_RELAXED, __HIP_MEMORY_SCOPE_AGENT);
  }
}

// ---- block-wide wait on 8 flags (epilogue only) ----
__device__ __forceinline__ void waitF8(int* __restrict__ flags, int g, int target,
                                       int tid) {
  if (tid < 8) {
    int it = 0;
    const int* p = flags + ((g << 3) + tid) * 16;
    while (__hip_atomic_load(p, __ATOMIC_RELAXED, __HIP_MEMORY_SCOPE_AGENT) < target) {
      if (++it > 300000) break;
      if (it > 32) __builtin_amdgcn_s_sleep(2);
    }
  }
  __syncthreads();
  __atomic_signal_fence(__ATOMIC_ACQUIRE);
}

// ---- epilogue gather: 8 blocks -> LDS ----
__device__ __forceinline__ void readBlks(const u64* __restrict__ exch, u64 slot0,
                                         int tid, u16* __restrict__ ldsH) {
  const int sp = tid >> 5, q2 = tid & 31;
  const u64* src = exch + (slot0 + sp) * 128 + (q2 << 2);
  const int m = q2 >> 1, half = q2 & 1;
  u16* dst = ldsH + m * HS + (sp << 5) + (half << 4);
#pragma unroll
  for (int j = 0; j < 4; j++) {
    u64 v = __hip_atomic_load(src + j,
                              __ATOMIC_RELAXED, __HIP_MEMORY_SCOPE_AGENT);
    *(u64*)(dst + (j << 2)) = v;
  }
}

extern "C" __global__ void __launch_bounds__(256, 1)
lstm_fused(const int* __restrict__ tokens, const void* __restrict__ emb,
           const void* __restrict__ W0, const void* __restrict__ R0, const void* __restrict__ b0,
           const void* __restrict__ W1, const void* __restrict__ R1, const void* __restrict__ b1,
           const void* __restrict__ Wout, const void* __restrict__ bout,
           void* __restrict__ outv) {
  extern __shared__ char smem[];

  const int tid = threadIdx.x;
  const int b = blockIdx.x;
  const int g = b & (NG - 1);
  const int w = b >> 4;
  const int role = w >> 3;             // 0 = layer-0 wg, 1 = layer-1 wg
  const int sl = w & 7;
  const int isF32 = g_isF32;

  auto ldf = [&](const void* p, int idx) -> float {
    return isF32 ? ((const float*)p)[idx] : bf2f(((const u16*)p)[idx]);
  };

  const int lane = tid & 63;
  const int wv = tid >> 6;            // wave = gate q (output tiles 2wv, 2wv+1)
  const int ml = lane & 15;
  const int quad = lane >> 4;
  const int um = tid >> 4;
  const int un = tid & 15;

  int* fl0 = g_f0 + (g << 3) * 16;    // this group's 8 h0 flags
  int* fl1 = g_f1 + (g << 3) * 16;
  int* flp = g_pr + (g << 3) * 16;

  if (role == 0) {
    // ================= LAYER-0 WORKGROUP =================
    u16* w0t = (u16*)(smem + L0_W0T);
    u16* r0t = (u16*)(smem + L0_R0T);
    u16* ldsX = (u16*)(smem + L0_X);
    float* ldsG = (float*)(smem + L0_G);
    u16* stg = (u16*)(smem + L0_STG);
    float* ldsB = (float*)(smem + L0_B);

    for (int i = tid; i < 128 * 128; i += 256) {
      int k = i >> 7, n = i & 127;
      int col = ((n >> 5) << 8) + (sl << 5) + (n & 31);
      w0t[n * EPAD + k] = f2bf(ldf(W0, k * 1024 + col));
    }
    for (int i = tid; i < 128 * 256; i += 256) {
      int k = i >> 7, n = i & 127;
      int col = ((n >> 5) << 8) + (sl << 5) + (n & 31);
      r0t[n * HS + k] = f2bf(ldf(R0, k * 1024 + col));
    }
    if (tid < 128) {
      int col = ((tid >> 5) << 8) + (sl << 5) + (tid & 31);
      ldsB[tid] = ldf(b0, col);
    }

    float cst[2] = {0.f, 0.f};
    const int tokBase = (g * MB + um) * T_STEPS;
    int prMin = 0;                    // cached min L1 progress (ring guard)

    float4 xfA, xfB; uint4 xbf;
    {
      int tok = tokens[tokBase];
      if (isF32) {
        const float* row = (const float*)emb + (u64)tok * E_SZ + (un << 3);
        xfA = *(const float4*)row; xfB = *(const float4*)(row + 4);
      } else {
        xbf = *(const uint4*)((const u16*)emb + (u64)tok * E_SZ + (un << 3));
      }
    }
    __syncthreads();

    const int row0 = (wv << 5) + ml;
    const u16* brA0 = w0t + row0 * EPAD + (quad << 3);
    const u16* brB0 = brA0 + (EPAD << 4);
    const u16* brA2 = r0t + row0 * HS + (quad << 3);
    const u16* brB2 = brA2 + (HS << 4);

    for (int t = 0; t < T_STEPS; t++) {
      // commit x_t
      {
        uint4 pk;
        if (isF32) {
          pk.x = (u32)f2bf(xfA.x) | ((u32)f2bf(xfA.y) << 16);
          pk.y = (u32)f2bf(xfA.z) | ((u32)f2bf(xfA.w) << 16);
          pk.z = (u32)f2bf(xfB.x) | ((u32)f2bf(xfB.y) << 16);
          pk.w = (u32)f2bf(xfB.z) | ((u32)f2bf(xfB.w) << 16);
        } else pk = xbf;
        *(uint4*)(ldsX + um * EPAD + (un << 3)) = pk;
      }
      __syncthreads();

      float ba = ldsB[row0], bb = ldsB[row0 + 16];
      f32x4 acA = {ba, ba, ba, ba}, acB = {bb, bb, bb, bb};

      // x_t @ W0 (no dependence on h0)
      {
        const u16* ar = ldsX + ml * EPAD + (quad << 3);
#pragma unroll
        for (int kc = 0; kc < 4; kc++) {
          bf16x8 av = *(const bf16x8*)(ar + kc * 32);
          acA = __builtin_amdgcn_mfma_f32_16x16x32_bf16(av, *(const bf16x8*)(brA0 + kc * 32), acA, 0, 0, 0);
          acB = __builtin_amdgcn_mfma_f32_16x16x32_bf16(av, *(const bf16x8*)(brB0 + kc * 32), acB, 0, 0, 0);
        }
      }

      // h0_{t-1} @ R0: one combined poll, then 16 pipelined frag loads
      if (t > 0) {
        wavePoll(fl0, t, nullptr, 0, lane);
        const u64 s0 = (u64)((((t - 1) & (RD - 1)) * NG + g) * NSL);
        bf16x8 fr[NSL];
#pragma unroll
        for (int j = 0; j < NSL; j++) fr[j] = loadFrag(g_exH0, s0 + j, ml, quad);
#pragma unroll
        for (int j = 0; j < NSL; j++) {
          acA = __builtin_amdgcn_mfma_f32_16x16x32_bf16(fr[j], *(const bf16x8*)(brA2 + (j << 5)), acA, 0, 0, 0);
          acB = __builtin_amdgcn_mfma_f32_16x16x32_bf16(fr[j], *(const bf16x8*)(brB2 + (j << 5)), acB, 0, 0, 0);
        }
      }

      // gates
#pragma unroll
      for (int r = 0; r < 4; r++) {
        int m = (quad << 2) + r;
        float gA = (wv == 2) ? tnh_(acA[r]) : sig_(acA[r]);
        float gB = (wv == 2) ? tnh_(acB[r]) : sig_(acB[r]);
        ldsG[row0 * 17 + m] = gA;
        ldsG[(row0 + 16) * 17 + m] = gB;
      }
      __syncthreads();

      // cell update -> stg
#pragma unroll
      for (int j = 0; j < 2; j++) {
        int idx = tid + (j << 8);
        int m = idx >> 5, uu = idx & 31;
        float iv = ldsG[uu * 17 + m];
        float fv = ldsG[(32 + uu) * 17 + m];
        float gv = ldsG[(64 + uu) * 17 + m];
        float ov = ldsG[(96 + uu) * 17 + m];
        float c = fv * cst[j] + iv * gv; cst[j] = c;
        stg[(m << 5) + uu] = f2bf(ov * tnh_(c));
      }
      __syncthreads();

      // ring guard, amortized: re-poll only when cached slack is spent
      if (t >= RD && prMin < t - RD + 1)
        prMin = wavePollMin(flp, t - RD + 1, lane);

      // post h0_t
      postBlk(g_exH0, (u64)(((t & (RD - 1)) * NG + g) * NSL + sl),
              g_f0, (g << 3) + sl, t + 1, tid, stg);

      // x_{t+1} prefetch in flight across next rendezvous
      if (t + 1 < T_STEPS) {
        int tok = tokens[tokBase + t + 1];
        if (isF32) {
          const float* row = (const float*)emb + (u64)tok * E_SZ + (un << 3);
          xfA = *(const float4*)row; xfB = *(const float4*)(row + 4);
        } else {
          xbf = *(const uint4*)((const u16*)emb + (u64)tok * E_SZ + (un << 3));
        }
      }
    }
  } else {
    // ================= LAYER-1 WORKGROUP =================
    u16* w1t = (u16*)(smem + L1_W1T);
    u16* r1t = (u16*)(smem + L1_R1T);
    u16* ldsEpi = (u16*)(smem + L1_EPI);
    float* ldsG = (float*)(smem + L1_G);
    u16* stg = (u16*)(smem + L1_STG);
    float* ldsB = (float*)(smem + L1_B);

    for (int i = tid; i < 128 * 256; i += 256) {
      int k = i >> 7, n = i & 127;
      int col = ((n >> 5) << 8) + (sl << 5) + (n & 31);
      w1t[n * HS + k] = f2bf(ldf(W1, k * 1024 + col));
      r1t[n * HS + k] = f2bf(ldf(R1, k * 1024 + col));
    }
    if (tid < 128) {
      int col = ((tid >> 5) << 8) + (sl << 5) + (tid & 31);
      ldsB[tid] = ldf(b1, col);
    }
    __syncthreads();

    float cst[2] = {0.f, 0.f};
    const int row0 = (wv << 5) + ml;
    const u16* brA1 = w1t + row0 * HS + (quad << 3);
    const u16* brB1 = brA1 + (HS << 4);
    const u16* brA2 = r1t + row0 * HS + (quad << 3);
    const u16* brB2 = brA2 + (HS << 4);

    for (int t = 0; t < T_STEPS; t++) {
      float ba = ldsB[row0], bb = ldsB[row0 + 16];
      f32x4 acA = {ba, ba, ba, ba}, acB = {bb, bb, bb, bb};

      // PHASE 1: h0_t (L0 runs ahead via ring -> flags nearly always set).
      // Do its load + W1 MFMAs BEFORE the pacing h1 observe, off the h1 chain.
      wavePoll(fl0, t + 1, nullptr, 0, lane);
      {
        bf16x8 fr0[NSL];
        const u64 s0 = (u64)(((t & (RD - 1)) * NG + g) * NSL);
#pragma unroll
        for (int j = 0; j < NSL; j++) fr0[j] = loadFrag(g_exH0, s0 + j, ml, quad);
#pragma unroll
        for (int j = 0; j < NSL; j++) {
          acA = __builtin_amdgcn_mfma_f32_16x16x32_bf16(fr0[j], *(const bf16x8*)(brA1 + (j << 5)), acA, 0, 0, 0);
          acB = __builtin_amdgcn_mfma_f32_16x16x32_bf16(fr0[j], *(const bf16x8*)(brB1 + (j << 5)), acB, 0, 0, 0);
        }
      }

      // PHASE 2: h1_{t-1} rendezvous — only h1 load + R1 MFMAs remain after it
      if (t > 0) {
        wavePoll(fl1, t, nullptr, 0, lane);
        bf16x8 fr1[NSL];
        const u64 s1 = (u64)((((t - 1) & 1) * NG + g) * NSL);
#pragma unroll
        for (int j = 0; j < NSL; j++) fr1[j] = loadFrag(g_exH1, s1 + j, ml, quad);
#pragma unroll
        for (int j = 0; j < NSL; j++) {
          acA = __builtin_amdgcn_mfma_f32_16x16x32_bf16(fr1[j], *(const bf16x8*)(brA2 + (j << 5)), acA, 0, 0, 0);
          acB = __builtin_amdgcn_mfma_f32_16x16x32_bf16(fr1[j], *(const bf16x8*)(brB2 + (j << 5)), acB, 0, 0, 0);
        }
      }

      // gates
#pragma unroll
      for (int r = 0; r < 4; r++) {
        int m = (quad << 2) + r;
        float gA = (wv == 2) ? tnh_(acA[r]) : sig_(acA[r]);
        float gB = (wv == 2) ? tnh_(acB[r]) : sig_(acB[r]);
        ldsG[row0 * 17 + m] = gA;
        ldsG[(row0 + 16) * 17 + m] = gB;
      }
      __syncthreads();

      // ring-slot release (all waves' h0 loads are consumed by now)
      if (tid == 0) {
        __atomic_signal_fence(__ATOMIC_RELEASE);
        __hip_atomic_store(g_pr + ((g << 3) + sl) * 16, t + 1,
                           __ATOMIC_RELAXED, __HIP_MEMORY_SCOPE_AGENT);
      }

      // cell update -> stg
#pragma unroll
      for (int j = 0; j < 2; j++) {
        int idx = tid + (j << 8);
        int m = idx >> 5, uu = idx & 31;
        float iv = ldsG[uu * 17 + m];
        float fv = ldsG[(32 + uu) * 17 + m];
        float gv = ldsG[(64 + uu) * 17 + m];
        float ov = ldsG[(96 + uu) * 17 + m];
        float c = fv * cst[j] + iv * gv; cst[j] = c;
        stg[(m << 5) + uu] = f2bf(ov * tnh_(c));
      }
      __syncthreads();

      // post h1_t
      postBlk(g_exH1, (u64)(((t & 1) * NG + g) * NSL + sl),
              g_f1, (g << 3) + sl, t + 1, tid, stg);
    }

    // epilogue: logits from h1_{T-1}
    if (sl == 0) {
      waitF8(g_f1, g, T_STEPS, tid);
      readBlks(g_exH1, (u64)(((T_STEPS - 1) & 1) * NG + g) * NSL, tid, ldsEpi);
      __syncthreads();
      float* woutf = ldsG;
      float* red = ldsG + 272;
      woutf[tid] = ldf(Wout, tid);
      __syncthreads();
      float p = 0.f;
#pragma unroll
      for (int j = 0; j < 16; j++)
        p += bf2f(ldsEpi[um * HS + (un << 4) + j]) * woutf[(un << 4) + j];
      red[um * 17 + un] = p;
      __syncthreads();
      if (tid < 16) {
        float sum = ldf(bout, 0);
#pragma unroll
        for (int j = 0; j < 16; j++) sum += red[tid * 17 + j];
        float val = sig_(sum);
        if (isF32) ((float*)outv)[g * MB + tid] = val;
        else       ((u16*)outv)[g * MB + tid] = f2bf(val);
      }
    }
  }
}

extern "C" void kernel_launch(void* const* d_in, const int* in_sizes, int n_in,
                              void* d_out, int out_size, void* d_ws, size_t ws_size,
                              hipStream_t stream) {
  const int* tokens = (const int*)d_in[0];
  const void* emb  = d_in[1];
  const void* W0   = d_in[2];
  const void* R0   = d_in[3];
  const void* b0   = d_in[4];
  const void* W1   = d_in[5];
  const void* R1   = d_in[6];
  const void* b1   = d_in[7];
  const void* Wout = d_in[8];
  const void* bout = d_in[9];

  hipFuncSetAttribute((const void*)lstm_fused,
                      hipFuncAttributeMaxDynamicSharedMemorySize, SMEM_TOTAL);

  dtype_probe<<<dim3(1), dim3(256), 0, stream>>>(W0);

  // 256 wgs (16 groups x (8 L0 + 8 L1)), 1 wg/CU: co-resident.
  lstm_fused<<<dim3(256), dim3(256), SMEM_TOTAL, stream>>>(
      tokens, emb, W0, R0, b0, W1, R1, b1, Wout, bout, d_out);
}